// Round 14
// baseline (145.230 us; speedup 1.0000x reference)
//
#include <hip/hip_runtime.h>
#include <math.h>
#include <stdint.h>

#define NV 50000      // visible nodes
#define NH 5000       // hidden nodes
#define NN 55000      // total nodes
#define NB4 1252      // fine buckets: k>>2, 4 k's each (1252*4 = 5008 >= 5000)
#define NBP 1280      // padded bucket count (5 * 256, for the two-level scan)
#define BCAP 1024     // region capacity per bucket (mean ~800, +8 sigma)
#define KSLOT 384     // per-k staging cap (mean 200, +13 sigma)
#define CHUNK 4096    // coarse-pass edges per block

// ws layout:
//   bits       : 0       , NV*4 u32   = 800000 B (128-bit spin mask per visible)
//   coarse_cnt : 800000  , NBP u32    = 5120 B
//   recs       : 805376  , NB4*BCAP*8 = 10.26 MB (uint2 {v | k<<16, w_bits})

// sign-select mask: 0xFFFFFFFF if bit bsh of word set, else 0
__device__ __forceinline__ uint32_t selmask(uint32_t word, uint32_t bsh) {
    return (uint32_t)((int32_t)(word << (31u - bsh)) >> 31);
}

// Pass 0: bit-pack s; block 0 zeros coarse_cnt (replaces hipMemsetAsync).
__global__ void __launch_bounds__(256) pack_zero_kernel(
        const int* __restrict__ s, uint32_t* __restrict__ bits,
        uint32_t* __restrict__ coarse_cnt) {
    if (blockIdx.x == 0)
        for (int i = threadIdx.x; i < NBP; i += 256) coarse_cnt[i] = 0u;
    int tid = blockIdx.x * 256 + threadIdx.x;
    int v = tid >> 2;
    int g = tid & 3;
    if (v >= NV) return;
    const int* col = s + (size_t)g * 32 * NN + v;
    uint32_t w = 0;
#pragma unroll
    for (int j = 0; j < 32; ++j)
        w |= (uint32_t)(col[(size_t)j * NN] & 1) << j;
    bits[(size_t)v * 4 + g] = w;   // consecutive tid -> consecutive addresses
}

// Pass A: fine split to 1252 buckets of 4 k's (was 313 x 16k). Counting-sort
// each 4096-edge chunk in LDS, reserve contiguous global runs, drain staged
// records LINEARLY -> coalesced HBM writes. Full k stored in the record
// (v fits 16 bits, k fits 13), so the drain recomputes each record's dest
// from the record itself — no dst array (-16 KB LDS). Two-level prefix scan:
// per-thread serial over 5 buckets + 256-wide Hillis-Steele on thread sums.
__global__ void __launch_bounds__(256) coarse_split_kernel(
        const int4* __restrict__ seg4, const int4* __restrict__ adj4,
        const float4* __restrict__ quad4,
        uint32_t* __restrict__ coarse_cnt, uint2* __restrict__ recs, int E) {
    __shared__ uint32_t hist[NBP];       // per-bucket counts
    __shared__ uint32_t locex[NBP];      // exclusive prefix (staging layout)
    __shared__ uint32_t cur[NBP];        // staging cursor
    __shared__ uint32_t gbase[NBP];      // reserved global run base
    __shared__ uint32_t wsum[256];       // scan temp
    __shared__ __align__(16) uint2 st[CHUNK];   // 32 KB staging
    const int tid = threadIdx.x;
    for (int i = tid; i < NBP; i += 256) hist[i] = 0u;
    __syncthreads();

    const int c0 = blockIdx.x * CHUNK;
    const int nloc = min(CHUNK, E - c0);         // E, c0 multiples of 4
    int kreg[16];
    // phase 1: histogram (seg only; k kept in registers)
#pragma unroll
    for (int j = 0; j < 4; ++j) {
        int t4 = (c0 >> 2) + j * 256 + tid;
        bool ok = t4 < ((c0 + nloc) >> 2);
        int4 sg = ok ? seg4[t4] : make_int4(-1, -1, -1, -1);
        kreg[j * 4 + 0] = sg.x; kreg[j * 4 + 1] = sg.y;
        kreg[j * 4 + 2] = sg.z; kreg[j * 4 + 3] = sg.w;
        if (ok) {
            atomicAdd(&hist[sg.x >> 2], 1u);
            atomicAdd(&hist[sg.y >> 2], 1u);
            atomicAdd(&hist[sg.z >> 2], 1u);
            atomicAdd(&hist[sg.w >> 2], 1u);
        }
    }
    __syncthreads();
    // phase 2a: reserve global runs
    for (int i = tid; i < NB4; i += 256)
        gbase[i] = atomicAdd(&coarse_cnt[i], hist[i]);
    // phase 2b: two-level exclusive scan over NBP = 5*256 entries
    uint32_t hh[5];
    {
        int base = tid * 5;
        uint32_t tot = 0;
#pragma unroll
        for (int t = 0; t < 5; ++t) { hh[t] = hist[base + t]; tot += hh[t]; }
        wsum[tid] = tot;
        __syncthreads();
        for (int d = 1; d < 256; d <<= 1) {
            uint32_t v = (tid >= d) ? wsum[tid - d] : 0u;
            __syncthreads();
            wsum[tid] += v;
            __syncthreads();
        }
        uint32_t off = wsum[tid] - tot;          // exclusive across threads
#pragma unroll
        for (int t = 0; t < 5; ++t) { locex[base + t] = off; off += hh[t]; }
    }
    __syncthreads();
    for (int i = tid; i < NBP; i += 256) cur[i] = locex[i];
    __syncthreads();
    // phase 3: place records into bucket-sorted staging
#pragma unroll
    for (int j = 0; j < 4; ++j) {
        int t4 = (c0 >> 2) + j * 256 + tid;
        if (t4 < ((c0 + nloc) >> 2)) {
            int4 a = adj4[t4];
            float4 q = quad4[t4];   // flat_j_idx == arange(E)
#pragma unroll
            for (int cmp = 0; cmp < 4; ++cmp) {
                int k = kreg[j * 4 + cmp];
                int v = (cmp == 0) ? a.x : (cmp == 1) ? a.y : (cmp == 2) ? a.z : a.w;
                float w = (cmp == 0) ? q.x : (cmp == 1) ? q.y : (cmp == 2) ? q.z : q.w;
                uint32_t slot = atomicAdd(&cur[k >> 2], 1u);
                st[slot] = make_uint2((uint32_t)v | ((uint32_t)k << 16),
                                      __float_as_uint(w));
            }
        }
    }
    __syncthreads();
    // phase 4: linear drain; dest recomputed from the record's own k
    for (int i = tid; i < nloc; i += 256) {
        uint2 r = st[i];
        uint32_t b = r.x >> 18;                  // k>>2
        uint32_t rank = gbase[b] + ((uint32_t)i - locex[b]);
        if (rank < BCAP) recs[(size_t)b * BCAP + rank] = r;
    }
}

// Pass B: per-bucket field. Block = one fine bucket (4 k's); reads EXACTLY
// its own region (~800 recs, 100% match — kills R11's 4x scan amplification
// and filter divergence). Stage: one coalesced region read + full-lane-active
// bits4 gather per record, direct into word-major rows (position via
// 4-counter LDS atomic); sum_w in registers -> shuffle + LDS atomic.
// Accumulate: R11's measured-best form (selmask, 2 b128/4recs per thread).
// Out: float4 of 4 adjacent k's; 4 consecutive buckets (one 64B out-line)
// land on one XCD via the swizzle.
__global__ void __launch_bounds__(256) field_kernel(
        const uint32_t* __restrict__ coarse_cnt, const uint2* __restrict__ recs,
        const uint4* __restrict__ bits4, const float* __restrict__ linear,
        float* __restrict__ out) {
    const int x = blockIdx.x;
    const int bkt = (x & 7) * 157 + (x >> 3);   // XCD-contiguous bucket index
    if (bkt >= NB4) return;                     // 4 idle blocks
    const int tid = threadIdx.x;

    __shared__ uint32_t cur4[4];
    __shared__ float swp[4];
    __shared__ __align__(16) uint32_t rows[4][5][KSLOT];   // 30.7 KB
    __shared__ float part[4][256];                         // 4 KB

    if (tid < 4) { cur4[tid] = 0u; swp[tid] = 0.f; }
    __syncthreads();

    // phase 1: read region, gather bits, stage direct to rows (all lanes hot)
    int cnt = min((int)coarse_cnt[bkt], BCAP);
    const uint2* region = recs + (size_t)bkt * BCAP;
    float sw0 = 0.f, sw1 = 0.f, sw2 = 0.f, sw3 = 0.f;
    for (int i = tid; i < cnt; i += 256) {
        uint2 r = region[i];                    // coalesced
        int l = (int)((r.x >> 16) & 3u);
        uint4 mw = bits4[r.x & 0xFFFFu];        // full-lane-active gather
        uint32_t p = atomicAdd(&cur4[l], 1u);
        if (p < KSLOT) {
            rows[l][0][p] = mw.x;
            rows[l][1][p] = mw.y;
            rows[l][2][p] = mw.z;
            rows[l][3][p] = mw.w;
            rows[l][4][p] = r.y;
            float wv = __uint_as_float(r.y);
            if (l == 0) sw0 += wv;
            else if (l == 1) sw1 += wv;
            else if (l == 2) sw2 += wv;
            else sw3 += wv;
        }
    }
#pragma unroll
    for (int off = 32; off; off >>= 1) {
        sw0 += __shfl_down(sw0, off);
        sw1 += __shfl_down(sw1, off);
        sw2 += __shfl_down(sw2, off);
        sw3 += __shfl_down(sw3, off);
    }
    if ((tid & 63) == 0) {
        atomicAdd(&swp[0], sw0);
        atomicAdd(&swp[1], sw1);
        atomicAdd(&swp[2], sw2);
        atomicAdd(&swp[3], sw3);
    }
    __syncthreads();
    // pad each list's w-row to a multiple of 8 (word rows may stay garbage)
    if (tid < 4) {
        int c = min((int)cur4[tid], KSLOT);
        int T8 = (c + 7) & ~7;
        for (int t = c; t < T8; ++t) rows[tid][4][t] = 0u;
        cur4[tid] = (uint32_t)T8;
    }
    __syncthreads();

    // phase 2: accumulate — 256 threads = 128 batches x 2 record-halves
    const int b = tid & 127;
    const int grp = tid >> 7;
    const uint32_t bsh = (uint32_t)(b & 31);
    const int widx = b >> 5;
#pragma unroll
    for (int kk = 0; kk < 4; ++kk) {
        int T8 = (int)cur4[kk];
        const uint32_t* mrow = &rows[kk][widx][0];
        const uint32_t* wrow = &rows[kk][4][0];
        float a0 = 0.f, a1 = 0.f, a2 = 0.f, a3 = 0.f;
        for (int i = grp * 4; i < T8; i += 8) {
            uint4 mm = *(const uint4*)(mrow + i);   // broadcast ds_read_b128
            uint4 ww = *(const uint4*)(wrow + i);
            a0 += __uint_as_float(ww.x & selmask(mm.x, bsh));
            a1 += __uint_as_float(ww.y & selmask(mm.y, bsh));
            a2 += __uint_as_float(ww.z & selmask(mm.z, bsh));
            a3 += __uint_as_float(ww.w & selmask(mm.w, bsh));
        }
        part[kk][tid] = (a0 + a1) + (a2 + a3);
    }
    __syncthreads();

    // phase 3: output — float4 of 4 adjacent k's per batch
    if (tid < 128) {
        int k0 = bkt * 4;
        if (k0 + 3 < NH) {           // buckets 1250,1251 are out of range
            float4 o;
            float* op = (float*)&o;
#pragma unroll
            for (int kk = 0; kk < 4; ++kk) {
                float acc = part[kk][tid] + part[kk][tid + 128];
                float e = 2.f * acc - swp[kk] + linear[NV + k0 + kk];
                op[kk] = tanhf(-e);
            }
            *(float4*)(out + (size_t)tid * NH + k0) = o;  // k0 mult of 4 -> aligned
        }
    }
}

extern "C" void kernel_launch(void* const* d_in, const int* in_sizes, int n_in,
                              void* d_out, int out_size, void* d_ws, size_t ws_size,
                              hipStream_t stream) {
    const float* linear = (const float*)d_in[0];
    const float* quad   = (const float*)d_in[1];
    const int*   s      = (const int*)d_in[2];
    const int*   adj    = (const int*)d_in[3];
    const int*   seg    = (const int*)d_in[5];
    const int E = in_sizes[5];
    float* out = (float*)d_out;

    char* ws = (char*)d_ws;
    uint32_t* bits       = (uint32_t*)(ws);
    uint32_t* coarse_cnt = (uint32_t*)(ws + 800000);
    uint2*    recs       = (uint2*)   (ws + 805376);

    pack_zero_kernel<<<(NV * 4 + 255) / 256, 256, 0, stream>>>(s, bits, coarse_cnt);
    const int nchunk = (E + CHUNK - 1) / CHUNK;       // 245
    coarse_split_kernel<<<nchunk, 256, 0, stream>>>(
        (const int4*)seg, (const int4*)adj, (const float4*)quad, coarse_cnt, recs, E);
    field_kernel<<<1256, 256, 0, stream>>>(coarse_cnt, recs, (const uint4*)bits,
                                           linear, out);
}

// Round 15
// 136.172 us; speedup vs baseline: 1.0665x; 1.0665x over previous
//
#include <hip/hip_runtime.h>
#include <math.h>
#include <stdint.h>

#define NV 50000      // visible nodes
#define NH 5000       // hidden nodes
#define NN 55000      // total nodes
#define NCB 313       // coarse buckets: k>>4, 16 k's each (313*16 = 5008 >= 5000)
#define BCAP 4096     // region capacity per bucket (mean ~3195, +16 sigma)
#define KSLOT 384     // per-k staging cap (mean 200, +13 sigma)
#define CHUNK 4096    // coarse-pass edges per block

// ws layout:
//   bits       : 0       , NV*4 u32   = 800000 B (128-bit spin mask per visible)
//   coarse_cnt : 800000  , NCB u32    = 1252 B
//   recs       : 801280  , NCB*BCAP*8 = 10.26 MB (uint2 {v | (k&15)<<16, w_bits})

// sign-select mask: 0xFFFFFFFF if bit bsh of word set, else 0 (v_bfe_i32)
__device__ __forceinline__ uint32_t selmask(uint32_t word, uint32_t bsh) {
    return (uint32_t)((int32_t)(word << (31u - bsh)) >> 31);
}

// Pass 0: bit-pack s; block 0 zeros coarse_cnt (replaces hipMemsetAsync).
__global__ void __launch_bounds__(256) pack_zero_kernel(
        const int* __restrict__ s, uint32_t* __restrict__ bits,
        uint32_t* __restrict__ coarse_cnt) {
    if (blockIdx.x == 0)
        for (int i = threadIdx.x; i < NCB; i += 256) coarse_cnt[i] = 0u;
    int tid = blockIdx.x * 256 + threadIdx.x;
    int v = tid >> 2;
    int g = tid & 3;
    if (v >= NV) return;
    const int* col = s + (size_t)g * 32 * NN + v;
    uint32_t w = 0;
#pragma unroll
    for (int j = 0; j < 32; ++j)
        w |= (uint32_t)(col[(size_t)j * NN] & 1) << j;
    bits[(size_t)v * 4 + g] = w;   // consecutive tid -> consecutive addresses
}

// Pass A: coarse split (R10 form — proven). Counting-sort each 4096-edge
// chunk by bucket (k>>4) in LDS, reserve contiguous global runs, drain
// staged records LINEARLY -> coalesced HBM writes (avg run 13 recs = 104 B;
// R14 showed finer buckets shrink runs to 26 B and regress).
__global__ void __launch_bounds__(256) coarse_split_kernel(
        const int4* __restrict__ seg4, const int4* __restrict__ adj4,
        const float4* __restrict__ quad4,
        uint32_t* __restrict__ coarse_cnt, uint2* __restrict__ recs, int E) {
    __shared__ uint32_t hist[320];       // per-bucket counts (padded to scan width)
    __shared__ uint32_t loc[320];        // inclusive prefix
    __shared__ uint32_t cur[NCB];        // staging cursor
    __shared__ uint32_t gbase[NCB];      // reserved global run base
    __shared__ __align__(16) uint2 st[CHUNK];   // 32 KB staging
    __shared__ uint32_t dst[CHUNK];             // absolute dest, ~0u = dropped
    const int tid = threadIdx.x;
    for (int i = tid; i < 320; i += 256) hist[i] = 0u;
    __syncthreads();

    const int c0 = blockIdx.x * CHUNK;
    const int nloc = min(CHUNK, E - c0);         // E, c0 multiples of 4
    int kreg[16];
#pragma unroll
    for (int j = 0; j < 4; ++j) {
        int t4 = (c0 >> 2) + j * 256 + tid;
        bool ok = t4 < ((c0 + nloc) >> 2);
        int4 sg = ok ? seg4[t4] : make_int4(-1, -1, -1, -1);
        kreg[j * 4 + 0] = sg.x; kreg[j * 4 + 1] = sg.y;
        kreg[j * 4 + 2] = sg.z; kreg[j * 4 + 3] = sg.w;
        if (ok) {
            atomicAdd(&hist[sg.x >> 4], 1u);
            atomicAdd(&hist[sg.y >> 4], 1u);
            atomicAdd(&hist[sg.z >> 4], 1u);
            atomicAdd(&hist[sg.w >> 4], 1u);
        }
    }
    __syncthreads();
    for (int i = tid; i < NCB; i += 256)
        gbase[i] = atomicAdd(&coarse_cnt[i], hist[i]);
    for (int i = tid; i < 320; i += 256) loc[i] = hist[i];
    __syncthreads();
    for (int d = 1; d < 320; d <<= 1) {          // Hillis-Steele scan
        uint32_t v0 = 0, v1 = 0;
        int i1 = tid + 256;
        if (tid >= d) v0 = loc[tid - d];
        if (i1 < 320 && i1 >= d) v1 = loc[i1 - d];
        __syncthreads();
        if (tid >= d) loc[tid] += v0;
        if (i1 < 320 && i1 >= d) loc[i1] += v1;
        __syncthreads();
    }
    for (int i = tid; i < NCB; i += 256) cur[i] = loc[i] - hist[i];  // exclusive
    __syncthreads();
#pragma unroll
    for (int j = 0; j < 4; ++j) {
        int t4 = (c0 >> 2) + j * 256 + tid;
        if (t4 < ((c0 + nloc) >> 2)) {
            int4 a = adj4[t4];
            float4 q = quad4[t4];   // flat_j_idx == arange(E)
#pragma unroll
            for (int cmp = 0; cmp < 4; ++cmp) {
                int k = kreg[j * 4 + cmp];
                int v = (cmp == 0) ? a.x : (cmp == 1) ? a.y : (cmp == 2) ? a.z : a.w;
                float w = (cmp == 0) ? q.x : (cmp == 1) ? q.y : (cmp == 2) ? q.z : q.w;
                int bk = k >> 4;
                uint32_t slot = atomicAdd(&cur[bk], 1u);
                uint32_t rank = gbase[bk] + (slot - (loc[bk] - hist[bk]));
                st[slot] = make_uint2((uint32_t)v | ((uint32_t)(k & 15) << 16),
                                      __float_as_uint(w));
                dst[slot] = (rank < BCAP) ? (uint32_t)bk * BCAP + rank : ~0u;
            }
        }
    }
    __syncthreads();
    for (int i = tid; i < nloc; i += 256) {
        uint32_t d = dst[i];
        if (d != ~0u) recs[d] = st[i];
    }
}

// Pass B: quarter-bucket field (R11 form — measured best). Block = 4 k's.
// Scan region -> compact st4 (compaction BEFORE gather keeps the bits4
// gathers full-lane-active; R12's inline gather regressed). Stage per
// 128-thread group, accumulate via broadcast ds_read_b128 with selmask
// (R13's halved-LDS variant regressed: not LDS-issue-bound), out float2.
// Swizzle puts a bucket's 4 quarters on one XCD (full 64B out-line).
__global__ void __launch_bounds__(256) quarter_field_kernel(
        const uint32_t* __restrict__ coarse_cnt, const uint2* __restrict__ recs,
        const uint4* __restrict__ bits4, const float* __restrict__ linear,
        float* __restrict__ out) {
    const int x = blockIdx.x;
    const int j = (x & 7) * 157 + (x >> 3);   // XCD-contiguous quarter index
    const int bkt = j >> 2;
    const int q = j & 3;
    if (bkt >= NCB) return;                   // 4 idle blocks (j 1252..1255)
    const int tid = threadIdx.x;

    __shared__ uint32_t cur4[4];
    __shared__ float swp[4];                              // per-wave sum_w partials
    __shared__ __align__(16) uint2 st4[4][KSLOT];         // 12.3 KB
    __shared__ __align__(16) uint32_t rows[2][5][KSLOT];  // 15.4 KB
    __shared__ float part[2][256];                        // 2 KB

    if (tid < 4) cur4[tid] = 0u;
    __syncthreads();

    // single scan of the bucket region: keep records with kl>>2 == q
    int cnt = (int)min(coarse_cnt[bkt], (uint32_t)BCAP);
    const uint2* region = recs + (size_t)bkt * BCAP;
    for (int i = tid; i < cnt; i += 256) {
        uint2 r = region[i];
        int kl = (int)((r.x >> 16) & 15u);
        if ((kl >> 2) == q) {
            uint32_t p = atomicAdd(&cur4[kl & 3], 1u);
            if (p < KSLOT) st4[kl & 3][p] = r;
        }
    }
    __syncthreads();

    const int b = tid & 127;
    const int grp = tid >> 7;         // 0/1
    const uint32_t bsh = (uint32_t)(b & 31);
    const int widx = b >> 5;

    for (int rnd = 0; rnd < 2; ++rnd) {
        // stage: 128-thread group grp handles list kl = rnd*2+grp
        int kl = rnd * 2 + grp;
        int c = min((int)cur4[kl], KSLOT);
        int T8 = (c + 7) & ~7;
        float sw = 0.f;
        for (int t = c + b; t < T8; t += 128) rows[grp][4][t] = 0u;  // w=0 pad
        for (int t = b; t < c; t += 128) {
            uint2 r = st4[kl][t];
            uint4 mw = bits4[r.x & 0xFFFFu];
            rows[grp][0][t] = mw.x;
            rows[grp][1][t] = mw.y;
            rows[grp][2][t] = mw.z;
            rows[grp][3][t] = mw.w;
            rows[grp][4][t] = r.y;
            sw += __uint_as_float(r.y);
        }
#pragma unroll
        for (int off = 32; off; off >>= 1) sw += __shfl_down(sw, off);
        if ((tid & 63) == 0) swp[tid >> 6] = sw;   // waves 0,1 -> kl0; 2,3 -> kl1
        __syncthreads();

        // accumulate: 256 threads = 128 batches x 2 record-halves, per k
#pragma unroll
        for (int kk = 0; kk < 2; ++kk) {
            int T8k = (min((int)cur4[rnd * 2 + kk], KSLOT) + 7) & ~7;
            const uint32_t* mrow = rows[kk][widx];
            const uint32_t* wrow = rows[kk][4];
            float a0 = 0.f, a1 = 0.f, a2 = 0.f, a3 = 0.f;
            for (int i = grp * 4; i < T8k; i += 8) {
                uint4 mm = *(const uint4*)(mrow + i);   // broadcast ds_read_b128
                uint4 ww = *(const uint4*)(wrow + i);
                a0 += __uint_as_float(ww.x & selmask(mm.x, bsh));
                a1 += __uint_as_float(ww.y & selmask(mm.y, bsh));
                a2 += __uint_as_float(ww.z & selmask(mm.z, bsh));
                a3 += __uint_as_float(ww.w & selmask(mm.w, bsh));
            }
            part[kk][tid] = (a0 + a1) + (a2 + a3);
        }
        __syncthreads();
        if (tid < 128) {
            int k0 = bkt * 16 + q * 4 + rnd * 2;
            if (k0 + 1 < NH) {
                float acc0 = part[0][tid] + part[0][tid + 128];
                float acc1 = part[1][tid] + part[1][tid + 128];
                float e0 = 2.f * acc0 - (swp[0] + swp[1]) + linear[NV + k0];
                float e1 = 2.f * acc1 - (swp[2] + swp[3]) + linear[NV + k0 + 1];
                float2 o = make_float2(tanhf(-e0), tanhf(-e1));
                *(float2*)(out + (size_t)tid * NH + k0) = o;  // k0 even -> aligned
            }
        }
        __syncthreads();   // rows/part/swp reuse guard
    }
}

extern "C" void kernel_launch(void* const* d_in, const int* in_sizes, int n_in,
                              void* d_out, int out_size, void* d_ws, size_t ws_size,
                              hipStream_t stream) {
    const float* linear = (const float*)d_in[0];
    const float* quad   = (const float*)d_in[1];
    const int*   s      = (const int*)d_in[2];
    const int*   adj    = (const int*)d_in[3];
    const int*   seg    = (const int*)d_in[5];
    const int E = in_sizes[5];
    float* out = (float*)d_out;

    char* ws = (char*)d_ws;
    uint32_t* bits       = (uint32_t*)(ws);
    uint32_t* coarse_cnt = (uint32_t*)(ws + 800000);
    uint2*    recs       = (uint2*)   (ws + 801280);

    pack_zero_kernel<<<(NV * 4 + 255) / 256, 256, 0, stream>>>(s, bits, coarse_cnt);
    const int nchunk = (E + CHUNK - 1) / CHUNK;       // 245
    coarse_split_kernel<<<nchunk, 256, 0, stream>>>(
        (const int4*)seg, (const int4*)adj, (const float4*)quad, coarse_cnt, recs, E);
    quarter_field_kernel<<<1256, 256, 0, stream>>>(coarse_cnt, recs, (const uint4*)bits,
                                                   linear, out);
}